// Round 2
// baseline (195.662 us; speedup 1.0000x reference)
//
#include <hip/hip_runtime.h>
#include <hip/hip_cooperative_groups.h>
#include <math.h>

namespace cg = cooperative_groups;

#define NB 4096
#define ND 1024
#define SCALEF 20.0f

typedef __bf16 bf16_t;
typedef bf16_t bf16x4 __attribute__((ext_vector_type(4)));
typedef bf16_t bf16x8 __attribute__((ext_vector_type(8)));
typedef float floatx4 __attribute__((ext_vector_type(4)));

__device__ __forceinline__ void load16_to_lds(const void* g, void* l) {
    __builtin_amdgcn_global_load_lds(
        (const __attribute__((address_space(1))) void*)g,
        (__attribute__((address_space(3))) void*)l, 16, 0, 0);
}

// ---------------------------------------------------------------------------
// Single fused cooperative kernel. 256 blocks x 512 threads, 1 block/CU
// (128 KiB LDS). Phase 1: L2-normalize + fp32->bf16 (32 rows/block).
// Phase 2: 256x256 bf16 MFMA GEMM with ring-4 LDS + counted vmcnt, fused
// exp-sum + diag. Phase 3: loss finalize. grid.sync() between phases.
// ---------------------------------------------------------------------------
__global__ __launch_bounds__(512, 2) void mnrl_fused(
    const float* __restrict__ A, const float* __restrict__ P,
    bf16_t* __restrict__ Abf, bf16_t* __restrict__ Pbf,
    float* __restrict__ rowsum, float* __restrict__ diag,
    float* __restrict__ out) {
    __shared__ __align__(16) bf16_t lds_a[4][256 * 32];
    __shared__ __align__(16) bf16_t lds_b[4][256 * 32];

    cg::grid_group grid = cg::this_grid();

    int t = threadIdx.x;
    int lane = t & 63;
    int w = t >> 6;  // 0..7

    // ---------------- Phase 1: normalize + convert ----------------
    if (blockIdx.x == 0 && t == 0) out[0] = 0.0f;
    if (t < 16) rowsum[blockIdx.x * 16 + t] = 0.0f;
#pragma unroll
    for (int rr = 0; rr < 4; ++rr) {
        int row = blockIdx.x * 32 + w * 4 + rr;  // 0..8191
        bool is_a = row < NB;
        const float* src = is_a ? (A + (size_t)row * ND)
                                : (P + (size_t)(row - NB) * ND);
        bf16_t* dst = is_a ? (Abf + (size_t)row * ND)
                           : (Pbf + (size_t)(row - NB) * ND);
        float4 v[4];
        float ss = 0.0f;
#pragma unroll
        for (int i = 0; i < 4; ++i) {
            v[i] = ((const float4*)src)[i * 64 + lane];
            ss += v[i].x * v[i].x + v[i].y * v[i].y + v[i].z * v[i].z +
                  v[i].w * v[i].w;
        }
#pragma unroll
        for (int off = 32; off > 0; off >>= 1) ss += __shfl_xor(ss, off, 64);
        float inv = 1.0f / fmaxf(sqrtf(ss), 1e-8f);
#pragma unroll
        for (int i = 0; i < 4; ++i) {
            bf16x4 wv;
            wv[0] = (bf16_t)(v[i].x * inv);
            wv[1] = (bf16_t)(v[i].y * inv);
            wv[2] = (bf16_t)(v[i].z * inv);
            wv[3] = (bf16_t)(v[i].w * inv);
            ((bf16x4*)dst)[i * 64 + lane] = wv;
        }
    }

    grid.sync();

    // ---------------- Phase 2: GEMM + exp-sum + diag ----------------
    // XCD-aware swizzle (256 blocks, 8 XCDs).
    int bid = blockIdx.x;
    int swz = (bid & 7) * 32 + (bid >> 3);
    int tile_m = swz >> 4;
    int tile_n = swz & 15;

    int wm = w >> 2;  // 0..1  (128-row half)
    int wn = w & 3;   // 0..3  (64-col quarter)
    int quad = lane >> 4, l16 = lane & 15;

    const bf16_t* Abase = Abf + (size_t)tile_m * 256 * ND;
    const bf16_t* Pbase = Pbf + (size_t)tile_n * 256 * ND;

    // Staging: lane l -> row (l>>2), LDS slot (l&3); fetch global chunk
    // (l&3)^((l>>3)&3) so that slot s of row r holds chunk s ^ ((r>>1)&3).
    int srow = lane >> 2;
    int chunk = (lane & 3) ^ ((lane >> 3) & 3);
    const bf16_t* srcA0 = Abase + (size_t)(w * 32 + srow) * ND + chunk * 8;
    const bf16_t* srcA1 = srcA0 + (size_t)16 * ND;
    const bf16_t* srcP0 = Pbase + (size_t)(w * 32 + srow) * ND + chunk * 8;
    const bf16_t* srcP1 = srcP0 + (size_t)16 * ND;
    const int dst0 = w * 1024;
    const int dst1 = w * 1024 + 512;

    // Fragment read offsets (elements). Row stride 32 elems (64 B).
    int key = (l16 >> 1) & 3;
    int slot8 = (quad ^ key) * 8;
    int offA[8], offB[4];
#pragma unroll
    for (int mt = 0; mt < 8; ++mt)
        offA[mt] = (wm * 128 + mt * 16 + l16) * 32 + slot8;
#pragma unroll
    for (int nt = 0; nt < 4; ++nt)
        offB[nt] = (wn * 64 + nt * 16 + l16) * 32 + slot8;

    floatx4 acc[8][4];
#pragma unroll
    for (int mt = 0; mt < 8; ++mt)
#pragma unroll
        for (int nt = 0; nt < 4; ++nt) acc[mt][nt] = (floatx4){0.f, 0.f, 0.f, 0.f};

#define STAGE(KT)                                                   \
    {                                                               \
        int koff_ = (KT) * 32;                                      \
        int b_ = (KT) & 3;                                          \
        load16_to_lds(srcA0 + koff_, &lds_a[b_][dst0]);             \
        load16_to_lds(srcA1 + koff_, &lds_a[b_][dst1]);             \
        load16_to_lds(srcP0 + koff_, &lds_b[b_][dst0]);             \
        load16_to_lds(srcP1 + koff_, &lds_b[b_][dst1]);             \
    }

#define K_BODY(KT, DOSTAGE)                                                  \
    {                                                                        \
        int b_ = (KT) & 3;                                                   \
        if (DOSTAGE) STAGE((KT) + 3);                                        \
        bf16x8 af[8], bv[4];                                                 \
        _Pragma("unroll") for (int mt = 0; mt < 8; ++mt)                     \
            af[mt] = *(const bf16x8*)&lds_a[b_][offA[mt]];                   \
        _Pragma("unroll") for (int nt = 0; nt < 4; ++nt)                     \
            bv[nt] = *(const bf16x8*)&lds_b[b_][offB[nt]];                   \
        __builtin_amdgcn_s_setprio(1);                                       \
        _Pragma("unroll") for (int mt = 0; mt < 8; ++mt)                     \
            _Pragma("unroll") for (int nt = 0; nt < 4; ++nt)                 \
                acc[mt][nt] = __builtin_amdgcn_mfma_f32_16x16x32_bf16(       \
                    af[mt], bv[nt], acc[mt][nt], 0, 0, 0);                   \
        __builtin_amdgcn_s_setprio(0);                                       \
    }

    // Prologue: 3 K-tiles in flight (12 loads/thread).
    STAGE(0);
    STAGE(1);
    STAGE(2);

    for (int kt = 0; kt < 29; ++kt) {
        asm volatile("s_waitcnt vmcnt(8)" ::: "memory");
        __builtin_amdgcn_s_barrier();
        asm volatile("" ::: "memory");
        K_BODY(kt, 1);
    }
    asm volatile("s_waitcnt vmcnt(8)" ::: "memory");
    __builtin_amdgcn_s_barrier();
    asm volatile("" ::: "memory");
    K_BODY(29, 0);
    asm volatile("s_waitcnt vmcnt(4)" ::: "memory");
    __builtin_amdgcn_s_barrier();
    asm volatile("" ::: "memory");
    K_BODY(30, 0);
    asm volatile("s_waitcnt vmcnt(0)" ::: "memory");
    __builtin_amdgcn_s_barrier();
    asm volatile("" ::: "memory");
    K_BODY(31, 0);

#undef K_BODY
#undef STAGE

    // Epilogue. C/D layout: col = l16, row = quad*4 + r.
    bool diag_block = (tile_m == tile_n);
    float psum[8][4];
#pragma unroll
    for (int mt = 0; mt < 8; ++mt)
#pragma unroll
        for (int r = 0; r < 4; ++r) psum[mt][r] = 0.0f;

#pragma unroll
    for (int mt = 0; mt < 8; ++mt)
#pragma unroll
        for (int nt = 0; nt < 4; ++nt)
#pragma unroll
            for (int r = 0; r < 4; ++r) {
                float sc = SCALEF * acc[mt][nt][r];
                psum[mt][r] += __expf(sc - SCALEF);  // scores in [-20,20]
                if (diag_block) {
                    int rt = wm * 128 + mt * 16 + quad * 4 + r;
                    int ct = wn * 64 + nt * 16 + l16;
                    if (rt == ct) diag[tile_m * 256 + rt] = sc;
                }
            }

    // Cross-l16 reduce, then cross-wn reduce in LDS -> 1 atomic per row.
    float* part = (float*)&lds_a[0][0];  // [4 wn][256 rows]
#pragma unroll
    for (int mt = 0; mt < 8; ++mt)
#pragma unroll
        for (int r = 0; r < 4; ++r) {
            float v = psum[mt][r];
            v += __shfl_xor(v, 1, 64);
            v += __shfl_xor(v, 2, 64);
            v += __shfl_xor(v, 4, 64);
            v += __shfl_xor(v, 8, 64);
            if (l16 == 0) part[wn * 256 + wm * 128 + mt * 16 + quad * 4 + r] = v;
        }
    __syncthreads();
    if (t < 256) {
        float s = part[t] + part[256 + t] + part[512 + t] + part[768 + t];
        atomicAdd(&rowsum[tile_m * 256 + t], s);
    }

    grid.sync();

    // ---------------- Phase 3: finalize ----------------
    if (t < 16) {
        int i = blockIdx.x * 16 + t;
        float rs = __hip_atomic_load(&rowsum[i], __ATOMIC_RELAXED,
                                     __HIP_MEMORY_SCOPE_AGENT);
        float dg = __hip_atomic_load(&diag[i], __ATOMIC_RELAXED,
                                     __HIP_MEMORY_SCOPE_AGENT);
        float local = (logf(rs) + SCALEF) - dg;
        local += __shfl_xor(local, 1, 64);
        local += __shfl_xor(local, 2, 64);
        local += __shfl_xor(local, 4, 64);
        local += __shfl_xor(local, 8, 64);
        if (t == 0) atomicAdd(out, local * (1.0f / (float)NB));
    }
}

// ---------------------------------------------------------------------------
extern "C" void kernel_launch(void* const* d_in, const int* in_sizes, int n_in,
                              void* d_out, int out_size, void* d_ws, size_t ws_size,
                              hipStream_t stream) {
    const float* A = (const float*)d_in[0];
    const float* P = (const float*)d_in[1];

    bf16_t* Abf = (bf16_t*)d_ws;                        // 8 MiB
    bf16_t* Pbf = Abf + (size_t)NB * ND;                // 8 MiB
    float* rowsum = (float*)(Pbf + (size_t)NB * ND);    // 16 KiB
    float* diag = rowsum + NB;                          // 16 KiB
    float* out = (float*)d_out;

    void* args[] = {(void*)&A,      (void*)&P,    (void*)&Abf, (void*)&Pbf,
                    (void*)&rowsum, (void*)&diag, (void*)&out};
    hipLaunchCooperativeKernel((const void*)mnrl_fused, dim3(256), dim3(512),
                               args, 0, stream);
}

// Round 3
// 119.413 us; speedup vs baseline: 1.6385x; 1.6385x over previous
//
#include <hip/hip_runtime.h>
#include <math.h>

#define NB 4096
#define ND 1024
#define SCALEF 20.0f

typedef __bf16 bf16_t;
typedef bf16_t bf16x4 __attribute__((ext_vector_type(4)));
typedef bf16_t bf16x8 __attribute__((ext_vector_type(8)));
typedef float floatx4 __attribute__((ext_vector_type(4)));

__device__ __forceinline__ void load16_to_lds(const void* g, void* l) {
    __builtin_amdgcn_global_load_lds(
        (const __attribute__((address_space(1))) void*)g,
        (__attribute__((address_space(3))) void*)l, 16, 0, 0);
}

// ---------------------------------------------------------------------------
// Kernel 1: fused L2-normalize + fp32->bf16 convert. One wave per row.
// Also zeroes rowsum[] (A rows) and out[0].
// ---------------------------------------------------------------------------
__global__ __launch_bounds__(256) void mnrl_norm_cvt(
    const float* __restrict__ A, const float* __restrict__ P,
    bf16_t* __restrict__ Abf, bf16_t* __restrict__ Pbf,
    float* __restrict__ rowsum, float* __restrict__ out) {
    if (blockIdx.x == 0 && threadIdx.x == 0) out[0] = 0.0f;
    int row = blockIdx.x * 4 + (threadIdx.x >> 6);  // 0..8191
    int lane = threadIdx.x & 63;
    bool is_a = row < NB;
    const float* src = is_a ? (A + (size_t)row * ND)
                            : (P + (size_t)(row - NB) * ND);
    bf16_t* dst = is_a ? (Abf + (size_t)row * ND)
                       : (Pbf + (size_t)(row - NB) * ND);

    float4 v[4];
    float ss = 0.0f;
#pragma unroll
    for (int i = 0; i < 4; ++i) {
        v[i] = ((const float4*)src)[i * 64 + lane];
        ss += v[i].x * v[i].x + v[i].y * v[i].y + v[i].z * v[i].z + v[i].w * v[i].w;
    }
#pragma unroll
    for (int off = 32; off > 0; off >>= 1) ss += __shfl_xor(ss, off, 64);
    float inv = 1.0f / fmaxf(sqrtf(ss), 1e-8f);
#pragma unroll
    for (int i = 0; i < 4; ++i) {
        bf16x4 w;
        w[0] = (bf16_t)(v[i].x * inv);
        w[1] = (bf16_t)(v[i].y * inv);
        w[2] = (bf16_t)(v[i].z * inv);
        w[3] = (bf16_t)(v[i].w * inv);
        ((bf16x4*)dst)[i * 64 + lane] = w;
    }
    if (is_a && lane == 0) rowsum[row] = 0.0f;
}

// ---------------------------------------------------------------------------
// Kernel 2: 256x256-tile bf16 MFMA GEMM, 8 waves (2Mx4N), BK=32,
// ring-4 LDS buffer, lookahead-3 prefetch, counted vmcnt(8) (never 0 in
// main loop). NEW vs round 1: each K-step split into 2 template-style
// phases {ds_read quadrant ; stage half-tile ; s_barrier ; setprio MFMA*16},
// A-half staged in phase alpha, B-half in phase beta (3 barriers/step).
// Fused exp-sum (fixed shift 20) + diagonal extraction.
// ---------------------------------------------------------------------------
__global__ __launch_bounds__(512, 2) void mnrl_gemm_lse(
    const bf16_t* __restrict__ Abf, const bf16_t* __restrict__ Pbf,
    float* __restrict__ rowsum, float* __restrict__ diag) {
    __shared__ __align__(16) bf16_t lds_a[4][256 * 32];
    __shared__ __align__(16) bf16_t lds_b[4][256 * 32];

    // XCD-aware swizzle (256 blocks, 8 XCDs).
    int bid = blockIdx.x;
    int swz = (bid & 7) * 32 + (bid >> 3);
    int tile_m = swz >> 4;
    int tile_n = swz & 15;

    int t = threadIdx.x;
    int lane = t & 63;
    int w = t >> 6;           // 0..7
    int wm = w >> 2;          // 0..1  (128-row half)
    int wn = w & 3;           // 0..3  (64-col quarter)
    int quad = lane >> 4;
    int l16 = lane & 15;

    const bf16_t* Abase = Abf + (size_t)tile_m * 256 * ND;
    const bf16_t* Pbase = Pbf + (size_t)tile_n * 256 * ND;

    // Staging: lane l -> row (l>>2), LDS slot (l&3); fetch global chunk
    // (l&3)^((l>>3)&3) so that slot s of row r holds chunk s ^ ((r>>1)&3).
    int srow = lane >> 2;
    int chunk = (lane & 3) ^ ((lane >> 3) & 3);
    const bf16_t* srcA0 = Abase + (size_t)(w * 32 + srow) * ND + chunk * 8;
    const bf16_t* srcA1 = srcA0 + (size_t)16 * ND;
    const bf16_t* srcP0 = Pbase + (size_t)(w * 32 + srow) * ND + chunk * 8;
    const bf16_t* srcP1 = srcP0 + (size_t)16 * ND;
    const int dst0 = w * 1024;
    const int dst1 = w * 1024 + 512;

    // Fragment read offsets (elements). Row stride 32 elems (64 B).
    int key = (l16 >> 1) & 3;
    int slot8 = (quad ^ key) * 8;
    int offA[8], offB[4];
#pragma unroll
    for (int mt = 0; mt < 8; ++mt)
        offA[mt] = (wm * 128 + mt * 16 + l16) * 32 + slot8;
#pragma unroll
    for (int nt = 0; nt < 4; ++nt)
        offB[nt] = (wn * 64 + nt * 16 + l16) * 32 + slot8;

    floatx4 acc[8][4];
#pragma unroll
    for (int mt = 0; mt < 8; ++mt)
#pragma unroll
        for (int nt = 0; nt < 4; ++nt) acc[mt][nt] = (floatx4){0.f, 0.f, 0.f, 0.f};

#define STAGE(KT)                                                   \
    {                                                               \
        int koff_ = (KT) * 32;                                      \
        int b_ = (KT) & 3;                                          \
        load16_to_lds(srcA0 + koff_, &lds_a[b_][dst0]);             \
        load16_to_lds(srcA1 + koff_, &lds_a[b_][dst1]);             \
        load16_to_lds(srcP0 + koff_, &lds_b[b_][dst0]);             \
        load16_to_lds(srcP1 + koff_, &lds_b[b_][dst1]);             \
    }

    // Two-phase K-step body. Phase alpha: read A[0..3]+B[0..3] frags, issue
    // A-half stage for kt+3, barrier, 16 MFMA. Phase beta: read A[4..7],
    // issue B-half stage, barrier, 16 MFMA. Stage targets buf (kt+3)&3 ==
    // (kt-1)&3, whose reads all drained before this step's top barrier.
#define K_BODY(KT, DOSTAGE)                                                  \
    {                                                                        \
        int b_ = (KT) & 3;                                                   \
        bf16x8 af[8], bv[4];                                                 \
        _Pragma("unroll") for (int mt = 0; mt < 4; ++mt)                     \
            af[mt] = *(const bf16x8*)&lds_a[b_][offA[mt]];                   \
        _Pragma("unroll") for (int nt = 0; nt < 4; ++nt)                     \
            bv[nt] = *(const bf16x8*)&lds_b[b_][offB[nt]];                   \
        if (DOSTAGE) {                                                       \
            int koff_ = ((KT) + 3) * 32;                                     \
            int sb_ = ((KT) + 3) & 3;                                        \
            load16_to_lds(srcA0 + koff_, &lds_a[sb_][dst0]);                 \
            load16_to_lds(srcA1 + koff_, &lds_a[sb_][dst1]);                 \
        }                                                                    \
        __builtin_amdgcn_s_barrier();                                        \
        __builtin_amdgcn_s_setprio(1);                                       \
        _Pragma("unroll") for (int mt = 0; mt < 4; ++mt)                     \
            _Pragma("unroll") for (int nt = 0; nt < 4; ++nt)                 \
                acc[mt][nt] = __builtin_amdgcn_mfma_f32_16x16x32_bf16(       \
                    af[mt], bv[nt], acc[mt][nt], 0, 0, 0);                   \
        __builtin_amdgcn_s_setprio(0);                                       \
        _Pragma("unroll") for (int mt = 4; mt < 8; ++mt)                     \
            af[mt] = *(const bf16x8*)&lds_a[b_][offA[mt]];                   \
        if (DOSTAGE) {                                                       \
            int koff_ = ((KT) + 3) * 32;                                     \
            int sb_ = ((KT) + 3) & 3;                                        \
            load16_to_lds(srcP0 + koff_, &lds_b[sb_][dst0]);                 \
            load16_to_lds(srcP1 + koff_, &lds_b[sb_][dst1]);                 \
        }                                                                    \
        __builtin_amdgcn_s_barrier();                                        \
        __builtin_amdgcn_s_setprio(1);                                       \
        _Pragma("unroll") for (int mt = 4; mt < 8; ++mt)                     \
            _Pragma("unroll") for (int nt = 0; nt < 4; ++nt)                 \
                acc[mt][nt] = __builtin_amdgcn_mfma_f32_16x16x32_bf16(       \
                    af[mt], bv[nt], acc[mt][nt], 0, 0, 0);                   \
        __builtin_amdgcn_s_setprio(0);                                       \
    }

    // Prologue: 3 K-tiles in flight (12 load-instrs/wave).
    STAGE(0);
    STAGE(1);
    STAGE(2);

    // Steady state: at top of step kt, loads newer than kt's are kt+1's and
    // kt+2's (8 instrs) -> vmcnt(8) forces kt's 4 complete; barrier makes
    // them LDS-visible to all waves.
    for (int kt = 0; kt < 29; ++kt) {
        asm volatile("s_waitcnt vmcnt(8)" ::: "memory");
        __builtin_amdgcn_s_barrier();
        asm volatile("" ::: "memory");
        K_BODY(kt, 1);
    }
    asm volatile("s_waitcnt vmcnt(8)" ::: "memory");
    __builtin_amdgcn_s_barrier();
    asm volatile("" ::: "memory");
    K_BODY(29, 0);
    asm volatile("s_waitcnt vmcnt(4)" ::: "memory");
    __builtin_amdgcn_s_barrier();
    asm volatile("" ::: "memory");
    K_BODY(30, 0);
    asm volatile("s_waitcnt vmcnt(0)" ::: "memory");
    __builtin_amdgcn_s_barrier();
    asm volatile("" ::: "memory");
    K_BODY(31, 0);

#undef K_BODY
#undef STAGE

    // Epilogue. C/D layout: col = l16, row = quad*4 + r.
    bool diag_block = (tile_m == tile_n);
    float psum[8][4];
#pragma unroll
    for (int mt = 0; mt < 8; ++mt)
#pragma unroll
        for (int r = 0; r < 4; ++r) psum[mt][r] = 0.0f;

#pragma unroll
    for (int mt = 0; mt < 8; ++mt)
#pragma unroll
        for (int nt = 0; nt < 4; ++nt)
#pragma unroll
            for (int r = 0; r < 4; ++r) {
                float sc = SCALEF * acc[mt][nt][r];
                psum[mt][r] += __expf(sc - SCALEF);  // scores in [-20,20]
                if (diag_block) {
                    int rt = wm * 128 + mt * 16 + quad * 4 + r;
                    int ct = wn * 64 + nt * 16 + l16;
                    if (rt == ct) diag[tile_m * 256 + rt] = sc;
                }
            }

    // Cross-l16 reduce, then cross-wn reduce in LDS -> 1 atomic per row.
    // lds_a[0] last read at kt=28; all waves past several barriers since.
    float* part = (float*)&lds_a[0][0];  // [4 wn][256 rows]
#pragma unroll
    for (int mt = 0; mt < 8; ++mt)
#pragma unroll
        for (int r = 0; r < 4; ++r) {
            float v = psum[mt][r];
            v += __shfl_xor(v, 1, 64);
            v += __shfl_xor(v, 2, 64);
            v += __shfl_xor(v, 4, 64);
            v += __shfl_xor(v, 8, 64);
            if (l16 == 0) part[wn * 256 + wm * 128 + mt * 16 + quad * 4 + r] = v;
        }
    __syncthreads();
    if (t < 256) {
        float s = part[t] + part[256 + t] + part[512 + t] + part[768 + t];
        atomicAdd(&rowsum[tile_m * 256 + t], s);
    }
}

// ---------------------------------------------------------------------------
// Kernel 3: loss = mean(log(rowsum) + 20 - diag). 16 blocks, atomic merge.
// ---------------------------------------------------------------------------
__global__ __launch_bounds__(256) void mnrl_finalize(const float* __restrict__ rowsum,
                                                     const float* __restrict__ diag,
                                                     float* __restrict__ out) {
    int t = threadIdx.x;
    int i = blockIdx.x * 256 + t;  // 16*256 = 4096
    float local = (logf(rowsum[i]) + SCALEF) - diag[i];
#pragma unroll
    for (int off = 32; off > 0; off >>= 1) local += __shfl_down(local, off, 64);
    __shared__ float sred[4];
    if ((t & 63) == 0) sred[t >> 6] = local;
    __syncthreads();
    if (t == 0)
        atomicAdd(out, (sred[0] + sred[1] + sred[2] + sred[3]) * (1.0f / (float)NB));
}

// ---------------------------------------------------------------------------
extern "C" void kernel_launch(void* const* d_in, const int* in_sizes, int n_in,
                              void* d_out, int out_size, void* d_ws, size_t ws_size,
                              hipStream_t stream) {
    const float* A = (const float*)d_in[0];
    const float* P = (const float*)d_in[1];

    bf16_t* Abf = (bf16_t*)d_ws;                        // 8 MiB
    bf16_t* Pbf = Abf + (size_t)NB * ND;                // 8 MiB
    float* rowsum = (float*)(Pbf + (size_t)NB * ND);    // 16 KiB (zeroed in cvt)
    float* diag = rowsum + NB;                          // 16 KiB

    mnrl_norm_cvt<<<2 * NB / 4, 256, 0, stream>>>(A, P, Abf, Pbf, rowsum,
                                                  (float*)d_out);
    mnrl_gemm_lse<<<16 * 16, 512, 0, stream>>>(Abf, Pbf, rowsum, diag);
    mnrl_finalize<<<16, 256, 0, stream>>>(rowsum, diag, (float*)d_out);
}